// Round 17
// baseline (290.377 us; speedup 1.0000x reference)
//
#include <hip/hip_runtime.h>
#include <stdint.h>

#define D_IN 128
#define D_OUT 128
#define NREL 8
#define NBASE 4

typedef __attribute__((ext_vector_type(8))) short short8;
typedef __attribute__((ext_vector_type(4))) float floatx4;
typedef __attribute__((ext_vector_type(2))) float floatx2;

__device__ __forceinline__ unsigned short f2bf(float f) {
  unsigned int u = __float_as_uint(f);
  u += 0x7fffu + ((u >> 16) & 1u);
  return (unsigned short)(u >> 16);
}
__device__ __forceinline__ unsigned pack2bf(float lo, float hi) {
  return (unsigned)f2bf(lo) | ((unsigned)f2bf(hi) << 16);
}
__device__ __forceinline__ float bflo(unsigned int u) { return __uint_as_float(u << 16); }
__device__ __forceinline__ float bfhi(unsigned int u) { return __uint_as_float(u & 0xffff0000u); }

// ---------- 1) prep: cast X fp32->bf16 + build W2T + count (counts zeroed
// by hipMemsetAsync) ----------
// W2T[o][c] = w_bases[b][k][o], c = k*4+b  (bf16, [128][512])
__global__ void k_prep(const float4* __restrict__ X, ushort4* __restrict__ Xb, int n4,
                       const float* __restrict__ w_bases, unsigned short* __restrict__ W2T,
                       const int* __restrict__ edst, int* __restrict__ counts, int E) {
  int i = blockIdx.x * blockDim.x + threadIdx.x;
  if (i < n4) {
    float4 v = X[i];
    ushort4 o;
    o.x = f2bf(v.x); o.y = f2bf(v.y); o.z = f2bf(v.z); o.w = f2bf(v.w);
    Xb[i] = o;
  }
  if (i < 128 * 512) {
    int o = i >> 9, c = i & 511;
    int k = c >> 2, b = c & 3;
    W2T[i] = f2bf(w_bases[(b * D_IN + k) * D_OUT + o]);
  }
  if (i < E) atomicAdd(&counts[edst[i]], 1);
}

// ---------- 2) CSR build (two-kernel scan: R12 proved serial-lookback = 103us) --
__global__ void k_scan1(const int* __restrict__ counts, int* __restrict__ localsc,
                        int* __restrict__ bsum, int Nn) {
  __shared__ int s[256];
  int i = blockIdx.x * 256 + threadIdx.x;
  int v = (i < Nn) ? counts[i] : 0;
  s[threadIdx.x] = v;
  __syncthreads();
  for (int off = 1; off < 256; off <<= 1) {
    int t = 0;
    if (threadIdx.x >= off) t = s[threadIdx.x - off];
    __syncthreads();
    s[threadIdx.x] += t;
    __syncthreads();
  }
  if (i < Nn) localsc[i] = s[threadIdx.x] - v;
  if (threadIdx.x == 255) bsum[blockIdx.x] = s[255];
}

__global__ void k_scan23(const int* __restrict__ localsc, const int* __restrict__ bsum,
                         int* __restrict__ offsets, int* __restrict__ cursor, int Nn, int E) {
  __shared__ int red[256];
  int acc = 0;
  for (int j = threadIdx.x; j < blockIdx.x; j += 256) acc += bsum[j];
  red[threadIdx.x] = acc;
  __syncthreads();
  for (int off = 128; off > 0; off >>= 1) {
    if (threadIdx.x < off) red[threadIdx.x] += red[threadIdx.x + off];
    __syncthreads();
  }
  int pref = red[0];
  int i = blockIdx.x * 256 + threadIdx.x;
  if (i < Nn) {
    int v = localsc[i] + pref;
    offsets[i] = v;
    cursor[i] = v;
  }
  if (i == 0) offsets[Nn] = E;
}

// Slim SoA bucket: srcs[] u32 + vrs[] u32 = (val & ~7) | rel  (rel in the 3
// mantissa LSBs, <=2^-20 rel err — numeric path hardware-verified PASS R6/R15).
__global__ void k_bucket(const int* __restrict__ src, const int* __restrict__ dst,
                         const int* __restrict__ rel, const float* __restrict__ val,
                         int* __restrict__ cursor, unsigned* __restrict__ srcs,
                         unsigned* __restrict__ vrs, int E) {
  int i = blockIdx.x * blockDim.x + threadIdx.x;
  if (i >= E) return;
  int d = dst[i];
  int pos = atomicAdd(&cursor[d], 1);
  srcs[pos] = (unsigned)src[i];
  vrs[pos] = (__float_as_uint(val[i]) & ~7u) | (unsigned)rel[i];
}

// ---------- 3) fused: per-dst basis aggregation (LDS) + MFMA transform ----------
// R15-verbatim body (81.3us measured, best; 6 variants confirm the gather-fill
// floor at ~1.6-1.8 TB/s). rowStart added: the grid is split into FOUR quarter
// dispatches (~20us each) purely as a rocprof diagnostic — lowers the top-5
// visibility threshold from ~81us to ~20us so build-chain kernels can surface.
__global__ __launch_bounds__(256, 4)
void k_agg_gemm(const unsigned* __restrict__ esrcs, const unsigned* __restrict__ evrs,
                const int* __restrict__ offsets, const unsigned* __restrict__ Xb2,
                const float* __restrict__ w_rel_g,
                const unsigned short* __restrict__ W2T, float* __restrict__ out,
                int rowStart, int Nn) {
  __shared__ __align__(16) unsigned short aggS[32][520];  // pitch 520: 2-way alias (free)
  __shared__ __align__(16) float wrS[NREL * NBASE];
  if (threadIdx.x < NREL * NBASE) wrS[threadIdx.x] = w_rel_g[threadIdx.x];
  __syncthreads();

  const int wave = threadIdx.x >> 6, lane = threadIdx.x & 63;
  const int d0 = rowStart + blockIdx.x * 32 + wave * 8;
  const floatx2 zf2 = {0.f, 0.f};
  const uint64_t xbase = (uint64_t)Xb2;       // byte base of bf16x2 rows (256B/row)
  const unsigned loff = (unsigned)lane * 4u;  // per-lane byte offset (VGPR)

  // lane l (0..8) loads offsets[d0+l]; readlane -> SGPR bounds
  int oidx = d0 + (lane < 8 ? lane : 8);
  if (oidx > Nn) oidx = Nn;
  const int offv = offsets[oidx];
  const int s0 = __builtin_amdgcn_readlane(offv, 0);
  const int e8 = __builtin_amdgcn_readlane(offv, 8);

  floatx2 a0 = zf2, a1 = zf2, a2 = zf2, a3 = zf2;
  int row = 0;
  int bnd = __builtin_amdgcn_readlane(offv, 1);

#define FLUSH()                                                      \
  do {                                                               \
    uint4 o_;                                                        \
    o_.x = pack2bf(a0.x, a1.x);                                      \
    o_.y = pack2bf(a2.x, a3.x);                                      \
    o_.z = pack2bf(a0.y, a1.y);                                      \
    o_.w = pack2bf(a2.y, a3.y);                                      \
    *(uint4*)&aggS[wave * 8 + row][lane * 8] = o_;                   \
    a0 = zf2; a1 = zf2; a2 = zf2; a3 = zf2;                          \
    ++row;                                                           \
    bnd = (row < 8) ? __builtin_amdgcn_readlane(offv, row + 1)       \
                    : 0x7fffffff;                                    \
  } while (0)

  // SSRC: 4 uniform src ids -> SGPRs (clamped: over-issue re-reads ce)
#define SSRC(S, BASE)                                                \
  do {                                                               \
    int b_ = (BASE);                                                 \
    int t0_ = b_ < ce ? b_ : ce;                                     \
    int t1_ = b_ + 1 < ce ? b_ + 1 : ce;                             \
    int t2_ = b_ + 2 < ce ? b_ + 2 : ce;                             \
    int t3_ = b_ + 3 < ce ? b_ + 3 : ce;                             \
    s##S##0 = esrcs[t0_]; s##S##1 = esrcs[t1_];                      \
    s##S##2 = esrcs[t2_]; s##S##3 = esrcs[t3_];                      \
  } while (0)

  // SVR: 4 uniform (val|rel) words -> SGPRs (clamped)
#define SVR(S, BASE)                                                 \
  do {                                                               \
    int b_ = (BASE);                                                 \
    int t0_ = b_ < ce ? b_ : ce;                                     \
    int t1_ = b_ + 1 < ce ? b_ + 1 : ce;                             \
    int t2_ = b_ + 2 < ce ? b_ + 2 : ce;                             \
    int t3_ = b_ + 3 < ce ? b_ + 3 : ce;                             \
    r##S##0 = evrs[t0_]; r##S##1 = evrs[t1_];                        \
    r##S##2 = evrs[t2_]; r##S##3 = evrs[t3_];                        \
  } while (0)

  // GLOAD: inline-asm gather (pinned — compiler can't sink/remat asm outputs)
#define GLOAD(Y, SRCID)                                              \
  do {                                                               \
    uint64_t ga_ = xbase + ((uint64_t)(SRCID) << 8);                 \
    asm volatile("global_load_dword %0, %1, %2"                      \
                 : "=v"(Y) : "v"(loff), "s"(ga_));                   \
  } while (0)

#define GATH(S)                                                      \
  do {                                                               \
    GLOAD(y##S##0, s##S##0); GLOAD(y##S##1, s##S##1);                \
    GLOAD(y##S##2, s##S##2); GLOAD(y##S##3, s##S##3);                \
  } while (0)

  // COEF: 4 edges' float4 coef = val * w_rel[rel] via LDS broadcast + muls
#define COEF1(C, RV)                                                 \
  do {                                                               \
    const float4 w_ = *(const float4*)&wrS[((RV) & 7u) * 4];         \
    const float v_ = __uint_as_float((RV) & ~7u);                    \
    (C) = make_float4(v_ * w_.x, v_ * w_.y, v_ * w_.z, v_ * w_.w);   \
  } while (0)

#define COEF(S)                                                      \
  do {                                                               \
    COEF1(c##S##0, r##S##0); COEF1(c##S##1, r##S##1);                \
    COEF1(c##S##2, r##S##2); COEF1(c##S##3, r##S##3);                \
  } while (0)

  // WAITG: oldest slot's 4 gathers done (3 younger slots = 12 remain);
  // sched_barrier fences the region (rule 18) AND pins the slot pipeline.
#define WAITG()                                                      \
  do {                                                               \
    asm volatile("s_waitcnt vmcnt(12)" ::: "memory");                \
    __builtin_amdgcn_sched_barrier(0);                               \
  } while (0)

  // ACCT1: one edge: scalar guard + boundary flush + 2 unpack + 8 fma
#define ACCT1(EI, C, Y)                                              \
  do {                                                               \
    if ((EI) < e8) {                                                 \
      while ((EI) == bnd) FLUSH();                                   \
      floatx2 x_;                                                    \
      x_.x = bflo(Y);                                                \
      x_.y = bfhi(Y);                                                \
      a0 += (C).x * x_;                                              \
      a1 += (C).y * x_;                                              \
      a2 += (C).z * x_;                                              \
      a3 += (C).w * x_;                                              \
    }                                                                \
  } while (0)

#define ACCT4(S, EI0)                                                \
  do {                                                               \
    ACCT1((EI0), c##S##0, y##S##0);                                  \
    ACCT1((EI0) + 1, c##S##1, y##S##1);                              \
    ACCT1((EI0) + 2, c##S##2, y##S##2);                              \
    ACCT1((EI0) + 3, c##S##3, y##S##3);                              \
  } while (0)

  if (s0 < e8) {
    const int ce = e8 - 1;
    unsigned s00, s01, s02, s03, s10, s11, s12, s13, s20, s21, s22, s23;
    unsigned s30, s31, s32, s33, s40, s41, s42, s43, s50, s51, s52, s53;
    unsigned r00, r01, r02, r03, r10, r11, r12, r13, r20, r21, r22, r23;
    unsigned r30, r31, r32, r33, r40, r41, r42, r43, r50, r51, r52, r53;
    unsigned y00, y01, y02, y03, y10, y11, y12, y13, y20, y21, y22, y23;
    unsigned y30, y31, y32, y33, y40, y41, y42, y43, y50, y51, y52, y53;
    float4 c00, c01, c02, c03, c10, c11, c12, c13, c20, c21, c22, c23;
    float4 c30, c31, c32, c33, c40, c41, c42, c43, c50, c51, c52, c53;
    // prologue: srcs for groups 0-4, vrs for 0-3, gathers 0-2, coefs 0-1
    SSRC(0, s0); SSRC(1, s0 + 4); SSRC(2, s0 + 8);
    SSRC(3, s0 + 12); SSRC(4, s0 + 16);
    SVR(0, s0); SVR(1, s0 + 4); SVR(2, s0 + 8); SVR(3, s0 + 12);
    GATH(0); GATH(1); GATH(2);
    COEF(0); COEF(1);
    int gi = s0;
    while (gi < e8) {
      // j=0
      GATH(3); SSRC(5, gi + 20); SVR(4, gi + 16); COEF(2); WAITG(); ACCT4(0, gi);
      // j=1
      GATH(4); SSRC(0, gi + 24); SVR(5, gi + 20); COEF(3); WAITG(); ACCT4(1, gi + 4);
      // j=2
      GATH(5); SSRC(1, gi + 28); SVR(0, gi + 24); COEF(4); WAITG(); ACCT4(2, gi + 8);
      // j=3
      GATH(0); SSRC(2, gi + 32); SVR(1, gi + 28); COEF(5); WAITG(); ACCT4(3, gi + 12);
      // j=4
      GATH(1); SSRC(3, gi + 36); SVR(2, gi + 32); COEF(0); WAITG(); ACCT4(4, gi + 16);
      // j=5
      GATH(2); SSRC(4, gi + 40); SVR(3, gi + 36); COEF(1); WAITG(); ACCT4(5, gi + 20);
      gi += 24;
    }
    // Drain: 12 outstanding tail gathers + pending s_loads must land BEFORE
    // their registers are reused (fenced both sides).
    __builtin_amdgcn_sched_barrier(0);
    asm volatile("s_waitcnt vmcnt(0) lgkmcnt(0)" ::: "memory");
    __builtin_amdgcn_sched_barrier(0);
  }
  while (row < 8) FLUSH();  // trailing (and fully-empty) rows

  __syncthreads();

  // ---- phase 2: 32x128 output tile via 16x16x32 MFMA, K=512 ----
  const int q = lane >> 4, r16 = lane & 15;
  const int wn = wave * 32;
  const floatx4 zero = {0.f, 0.f, 0.f, 0.f};
  floatx4 acc[2][2];
  acc[0][0] = zero; acc[0][1] = zero; acc[1][0] = zero; acc[1][1] = zero;

#pragma unroll 4
  for (int k0 = 0; k0 < 512; k0 += 32) {
    int ka = k0 + q * 8;
    short8 af[2], bfv[2];
    af[0] = *(const short8*)&aggS[r16][ka];
    af[1] = *(const short8*)&aggS[16 + r16][ka];
    bfv[0] = *(const short8*)(W2T + (size_t)(wn + r16) * 512 + ka);
    bfv[1] = *(const short8*)(W2T + (size_t)(wn + 16 + r16) * 512 + ka);
#pragma unroll
    for (int i = 0; i < 2; ++i)
#pragma unroll
      for (int j = 0; j < 2; ++j)
        acc[i][j] = __builtin_amdgcn_mfma_f32_16x16x32_bf16(af[i], bfv[j], acc[i][j], 0, 0, 0);
  }

  // epilogue: C/D layout col=lane&15, row=(lane>>4)*4+p  [m89/m91-verified]
#pragma unroll
  for (int i = 0; i < 2; ++i) {
#pragma unroll
    for (int j = 0; j < 2; ++j) {
#pragma unroll
      for (int p = 0; p < 4; ++p) {
        int prow = i * 16 + q * 4 + p;
        int col = wn + j * 16 + r16;
        int grow = rowStart + blockIdx.x * 32 + prow;
        if (grow < Nn) out[(size_t)grow * 128 + col] = acc[i][j][p];
      }
    }
  }
}

extern "C" void kernel_launch(void* const* d_in, const int* in_sizes, int n_in,
                              void* d_out, int out_size, void* d_ws, size_t ws_size,
                              hipStream_t stream) {
  const float* X = (const float*)d_in[0];
  const int* esrc = (const int*)d_in[1];
  const int* edst = (const int*)d_in[2];
  const int* erel = (const int*)d_in[3];
  const float* eval_ = (const float*)d_in[4];
  const float* w_bases = (const float*)d_in[5];
  const float* w_rel = (const float*)d_in[6];
  const int Nn = in_sizes[0] / D_IN;  // 100000
  const int E = in_sizes[1];          // 640000

  char* ws = (char*)d_ws;
  size_t off = 0;
  auto alloc = [&](size_t bytes) -> char* {
    char* p = ws + off;
    off += (bytes + 255) & ~(size_t)255;
    return p;
  };
  unsigned short* Xb = (unsigned short*)alloc((size_t)Nn * D_IN * 2);     // 25.6 MB
  unsigned short* W2T = (unsigned short*)alloc((size_t)128 * 512 * 2);    // 128 KB
  int* counts = (int*)alloc((size_t)Nn * 4);
  int* cursor = (int*)alloc((size_t)Nn * 4);
  int* offsets = (int*)alloc((size_t)(Nn + 1) * 4);
  int* localsc = (int*)alloc((size_t)Nn * 4);
  int* bsum = (int*)alloc(4096);
  unsigned* srcs = (unsigned*)alloc((size_t)(E + 64) * 4);                // 2.56 MB
  unsigned* vrs = (unsigned*)alloc((size_t)(E + 64) * 4);                 // 2.56 MB
  (void)ws_size;

  int n4 = Nn * D_IN / 4;  // 3.2M
  hipMemsetAsync(counts, 0, (size_t)Nn * 4, stream);
  k_prep<<<(n4 + 255) / 256, 256, 0, stream>>>((const float4*)X, (ushort4*)Xb, n4,
                                               w_bases, W2T, edst, counts, E);

  int nb = (Nn + 255) / 256;
  k_scan1<<<nb, 256, 0, stream>>>(counts, localsc, bsum, Nn);
  k_scan23<<<nb, 256, 0, stream>>>(localsc, bsum, offsets, cursor, Nn, E);
  k_bucket<<<(E + 255) / 256, 256, 0, stream>>>(esrc, edst, erel, eval_,
                                                cursor, srcs, vrs, E);

  // fused aggregation + transform, split into FOUR quarter-grids (diagnostic:
  // lowers the rocprof top-5 threshold to ~20us so build kernels surface)
  int quarter = ((Nn / 4) + 31) & ~31;  // 25024
  for (int qi = 0; qi < 4; ++qi) {
    int rs = qi * quarter;
    int rows = (qi == 3) ? (Nn - rs) : quarter;
    if (rows <= 0) break;
    k_agg_gemm<<<(rows + 31) / 32, 256, 0, stream>>>(srcs, vrs, offsets,
                                                     (const unsigned*)Xb, w_rel, W2T,
                                                     (float*)d_out, rs, Nn);
  }
}

// Round 18
// 244.393 us; speedup vs baseline: 1.1882x; 1.1882x over previous
//
#include <hip/hip_runtime.h>
#include <stdint.h>

#define D_IN 128
#define D_OUT 128
#define NREL 8
#define NBASE 4

typedef __attribute__((ext_vector_type(8))) short short8;
typedef __attribute__((ext_vector_type(4))) float floatx4;
typedef __attribute__((ext_vector_type(2))) float floatx2;

__device__ __forceinline__ unsigned short f2bf(float f) {
  unsigned int u = __float_as_uint(f);
  u += 0x7fffu + ((u >> 16) & 1u);
  return (unsigned short)(u >> 16);
}
__device__ __forceinline__ unsigned pack2bf(float lo, float hi) {
  return (unsigned)f2bf(lo) | ((unsigned)f2bf(hi) << 16);
}
__device__ __forceinline__ float bflo(unsigned int u) { return __uint_as_float(u << 16); }
__device__ __forceinline__ float bfhi(unsigned int u) { return __uint_as_float(u & 0xffff0000u); }

// ---------- 1) prep: cast X fp32->bf16 + build W2T + count (counts zeroed
// by hipMemsetAsync) ----------
// W2T[o][c] = w_bases[b][k][o], c = k*4+b  (bf16, [128][512])
__global__ void k_prep(const float4* __restrict__ X, ushort4* __restrict__ Xb, int n4,
                       const float* __restrict__ w_bases, unsigned short* __restrict__ W2T,
                       const int* __restrict__ edst, int* __restrict__ counts, int E) {
  int i = blockIdx.x * blockDim.x + threadIdx.x;
  if (i < n4) {
    float4 v = X[i];
    ushort4 o;
    o.x = f2bf(v.x); o.y = f2bf(v.y); o.z = f2bf(v.z); o.w = f2bf(v.w);
    Xb[i] = o;
  }
  if (i < 128 * 512) {
    int o = i >> 9, c = i & 511;
    int k = c >> 2, b = c & 3;
    W2T[i] = f2bf(w_bases[(b * D_IN + k) * D_OUT + o]);
  }
  if (i < E) atomicAdd(&counts[edst[i]], 1);
}

// ---------- 2) CSR build (two-kernel scan: R12 proved serial-lookback = 103us) --
__global__ void k_scan1(const int* __restrict__ counts, int* __restrict__ localsc,
                        int* __restrict__ bsum, int Nn) {
  __shared__ int s[256];
  int i = blockIdx.x * 256 + threadIdx.x;
  int v = (i < Nn) ? counts[i] : 0;
  s[threadIdx.x] = v;
  __syncthreads();
  for (int off = 1; off < 256; off <<= 1) {
    int t = 0;
    if (threadIdx.x >= off) t = s[threadIdx.x - off];
    __syncthreads();
    s[threadIdx.x] += t;
    __syncthreads();
  }
  if (i < Nn) localsc[i] = s[threadIdx.x] - v;
  if (threadIdx.x == 255) bsum[blockIdx.x] = s[255];
}

__global__ void k_scan23(const int* __restrict__ localsc, const int* __restrict__ bsum,
                         int* __restrict__ offsets, int* __restrict__ cursor, int Nn, int E) {
  __shared__ int red[256];
  int acc = 0;
  for (int j = threadIdx.x; j < blockIdx.x; j += 256) acc += bsum[j];
  red[threadIdx.x] = acc;
  __syncthreads();
  for (int off = 128; off > 0; off >>= 1) {
    if (threadIdx.x < off) red[threadIdx.x] += red[threadIdx.x + off];
    __syncthreads();
  }
  int pref = red[0];
  int i = blockIdx.x * 256 + threadIdx.x;
  if (i < Nn) {
    int v = localsc[i] + pref;
    offsets[i] = v;
    cursor[i] = v;
  }
  if (i == 0) offsets[Nn] = E;
}

// AoS bucket: ONE 8B uint2 store per edge = (src, (val&~7)|rel).
// [R17 PMC: two 4B scatters to two buffers -> WRITE_SIZE 69.7MB for 5.1MB of
// data (cross-XCD partial-line write-backs). One 8B store halves the distinct
// dirty (line,XCD) pairs.] vr packing hardware-verified PASS R6/R15.
__global__ void k_bucket(const int* __restrict__ src, const int* __restrict__ dst,
                         const int* __restrict__ rel, const float* __restrict__ val,
                         int* __restrict__ cursor, uint2* __restrict__ bucket, int E) {
  int i = blockIdx.x * blockDim.x + threadIdx.x;
  if (i >= E) return;
  int d = dst[i];
  int pos = atomicAdd(&cursor[d], 1);
  unsigned vr = (__float_as_uint(val[i]) & ~7u) | (unsigned)rel[i];
  bucket[pos] = make_uint2((unsigned)src[i], vr);
}

// ---------- 3) fused: per-dst basis aggregation (LDS) + MFMA transform ----------
// R15 body (81.3us measured best; 6 variants confirm the ~1.6-1.8 TB/s
// gather-fill floor), single dispatch (R17: quarter-split cost ~40us of
// boundary overhead). Records now AoS uint2 -> merged scalar s_load_dwordx2
// (slot s=src, r=vr from bucket[t].x/.y); leads unchanged: record load 2 steps
// before its GATH, COEF 2 before its ACCT, gathers 3 before consume.
__global__ __launch_bounds__(256, 4)
void k_agg_gemm(const uint2* __restrict__ ebuck, const int* __restrict__ offsets,
                const unsigned* __restrict__ Xb2, const float* __restrict__ w_rel_g,
                const unsigned short* __restrict__ W2T, float* __restrict__ out, int Nn) {
  __shared__ __align__(16) unsigned short aggS[32][520];  // pitch 520: 2-way alias (free)
  __shared__ __align__(16) float wrS[NREL * NBASE];
  if (threadIdx.x < NREL * NBASE) wrS[threadIdx.x] = w_rel_g[threadIdx.x];
  __syncthreads();

  const int wave = threadIdx.x >> 6, lane = threadIdx.x & 63;
  const int d0 = blockIdx.x * 32 + wave * 8;
  const floatx2 zf2 = {0.f, 0.f};
  const uint64_t xbase = (uint64_t)Xb2;       // byte base of bf16x2 rows (256B/row)
  const unsigned loff = (unsigned)lane * 4u;  // per-lane byte offset (VGPR)

  // lane l (0..8) loads offsets[d0+l]; readlane -> SGPR bounds
  int oidx = d0 + (lane < 8 ? lane : 8);
  if (oidx > Nn) oidx = Nn;
  const int offv = offsets[oidx];
  const int s0 = __builtin_amdgcn_readlane(offv, 0);
  const int e8 = __builtin_amdgcn_readlane(offv, 8);

  floatx2 a0 = zf2, a1 = zf2, a2 = zf2, a3 = zf2;
  int row = 0;
  int bnd = __builtin_amdgcn_readlane(offv, 1);

#define FLUSH()                                                      \
  do {                                                               \
    uint4 o_;                                                        \
    o_.x = pack2bf(a0.x, a1.x);                                      \
    o_.y = pack2bf(a2.x, a3.x);                                      \
    o_.z = pack2bf(a0.y, a1.y);                                      \
    o_.w = pack2bf(a2.y, a3.y);                                      \
    *(uint4*)&aggS[wave * 8 + row][lane * 8] = o_;                   \
    a0 = zf2; a1 = zf2; a2 = zf2; a3 = zf2;                          \
    ++row;                                                           \
    bnd = (row < 8) ? __builtin_amdgcn_readlane(offv, row + 1)       \
                    : 0x7fffffff;                                    \
  } while (0)

  // SREC: 4 uniform uint2 records -> SGPR pairs (clamped: over-issue re-reads ce)
#define SREC(S, BASE)                                                \
  do {                                                               \
    int b_ = (BASE);                                                 \
    int t0_ = b_ < ce ? b_ : ce;                                     \
    int t1_ = b_ + 1 < ce ? b_ + 1 : ce;                             \
    int t2_ = b_ + 2 < ce ? b_ + 2 : ce;                             \
    int t3_ = b_ + 3 < ce ? b_ + 3 : ce;                             \
    uint2 q0_ = ebuck[t0_], q1_ = ebuck[t1_];                        \
    uint2 q2_ = ebuck[t2_], q3_ = ebuck[t3_];                        \
    s##S##0 = q0_.x; r##S##0 = q0_.y;                                \
    s##S##1 = q1_.x; r##S##1 = q1_.y;                                \
    s##S##2 = q2_.x; r##S##2 = q2_.y;                                \
    s##S##3 = q3_.x; r##S##3 = q3_.y;                                \
  } while (0)

  // GLOAD: inline-asm gather (pinned — compiler can't sink/remat asm outputs)
#define GLOAD(Y, SRCID)                                              \
  do {                                                               \
    uint64_t ga_ = xbase + ((uint64_t)(SRCID) << 8);                 \
    asm volatile("global_load_dword %0, %1, %2"                      \
                 : "=v"(Y) : "v"(loff), "s"(ga_));                   \
  } while (0)

#define GATH(S)                                                      \
  do {                                                               \
    GLOAD(y##S##0, s##S##0); GLOAD(y##S##1, s##S##1);                \
    GLOAD(y##S##2, s##S##2); GLOAD(y##S##3, s##S##3);                \
  } while (0)

  // COEF: 4 edges' float4 coef = val * w_rel[rel] via LDS broadcast + muls
#define COEF1(C, RV)                                                 \
  do {                                                               \
    const float4 w_ = *(const float4*)&wrS[((RV) & 7u) * 4];         \
    const float v_ = __uint_as_float((RV) & ~7u);                    \
    (C) = make_float4(v_ * w_.x, v_ * w_.y, v_ * w_.z, v_ * w_.w);   \
  } while (0)

#define COEF(S)                                                      \
  do {                                                               \
    COEF1(c##S##0, r##S##0); COEF1(c##S##1, r##S##1);                \
    COEF1(c##S##2, r##S##2); COEF1(c##S##3, r##S##3);                \
  } while (0)

  // WAITG: oldest slot's 4 gathers done (3 younger slots = 12 remain);
  // sched_barrier fences the region (rule 18) AND pins the slot pipeline.
#define WAITG()                                                      \
  do {                                                               \
    asm volatile("s_waitcnt vmcnt(12)" ::: "memory");                \
    __builtin_amdgcn_sched_barrier(0);                               \
  } while (0)

  // ACCT1: one edge: scalar guard + boundary flush + 2 unpack + 8 fma
#define ACCT1(EI, C, Y)                                              \
  do {                                                               \
    if ((EI) < e8) {                                                 \
      while ((EI) == bnd) FLUSH();                                   \
      floatx2 x_;                                                    \
      x_.x = bflo(Y);                                                \
      x_.y = bfhi(Y);                                                \
      a0 += (C).x * x_;                                              \
      a1 += (C).y * x_;                                              \
      a2 += (C).z * x_;                                              \
      a3 += (C).w * x_;                                              \
    }                                                                \
  } while (0)

#define ACCT4(S, EI0)                                                \
  do {                                                               \
    ACCT1((EI0), c##S##0, y##S##0);                                  \
    ACCT1((EI0) + 1, c##S##1, y##S##1);                              \
    ACCT1((EI0) + 2, c##S##2, y##S##2);                              \
    ACCT1((EI0) + 3, c##S##3, y##S##3);                              \
  } while (0)

  if (s0 < e8) {
    const int ce = e8 - 1;
    unsigned s00, s01, s02, s03, s10, s11, s12, s13, s20, s21, s22, s23;
    unsigned s30, s31, s32, s33, s40, s41, s42, s43, s50, s51, s52, s53;
    unsigned r00, r01, r02, r03, r10, r11, r12, r13, r20, r21, r22, r23;
    unsigned r30, r31, r32, r33, r40, r41, r42, r43, r50, r51, r52, r53;
    unsigned y00, y01, y02, y03, y10, y11, y12, y13, y20, y21, y22, y23;
    unsigned y30, y31, y32, y33, y40, y41, y42, y43, y50, y51, y52, y53;
    float4 c00, c01, c02, c03, c10, c11, c12, c13, c20, c21, c22, c23;
    float4 c30, c31, c32, c33, c40, c41, c42, c43, c50, c51, c52, c53;
    // prologue: records for slots 0-4, gathers 0-2, coefs 0-1
    SREC(0, s0); SREC(1, s0 + 4); SREC(2, s0 + 8);
    SREC(3, s0 + 12); SREC(4, s0 + 16);
    GATH(0); GATH(1); GATH(2);
    COEF(0); COEF(1);
    int gi = s0;
    while (gi < e8) {
      // j=0
      GATH(3); SREC(5, gi + 20); COEF(2); WAITG(); ACCT4(0, gi);
      // j=1
      GATH(4); SREC(0, gi + 24); COEF(3); WAITG(); ACCT4(1, gi + 4);
      // j=2
      GATH(5); SREC(1, gi + 28); COEF(4); WAITG(); ACCT4(2, gi + 8);
      // j=3
      GATH(0); SREC(2, gi + 32); COEF(5); WAITG(); ACCT4(3, gi + 12);
      // j=4
      GATH(1); SREC(3, gi + 36); COEF(0); WAITG(); ACCT4(4, gi + 16);
      // j=5
      GATH(2); SREC(4, gi + 40); COEF(1); WAITG(); ACCT4(5, gi + 20);
      gi += 24;
    }
    // Drain: 12 outstanding tail gathers + pending s_loads must land BEFORE
    // their registers are reused (fenced both sides).
    __builtin_amdgcn_sched_barrier(0);
    asm volatile("s_waitcnt vmcnt(0) lgkmcnt(0)" ::: "memory");
    __builtin_amdgcn_sched_barrier(0);
  }
  while (row < 8) FLUSH();  // trailing (and fully-empty) rows

  __syncthreads();

  // ---- phase 2: 32x128 output tile via 16x16x32 MFMA, K=512 ----
  const int q = lane >> 4, r16 = lane & 15;
  const int wn = wave * 32;
  const floatx4 zero = {0.f, 0.f, 0.f, 0.f};
  floatx4 acc[2][2];
  acc[0][0] = zero; acc[0][1] = zero; acc[1][0] = zero; acc[1][1] = zero;

#pragma unroll 4
  for (int k0 = 0; k0 < 512; k0 += 32) {
    int ka = k0 + q * 8;
    short8 af[2], bfv[2];
    af[0] = *(const short8*)&aggS[r16][ka];
    af[1] = *(const short8*)&aggS[16 + r16][ka];
    bfv[0] = *(const short8*)(W2T + (size_t)(wn + r16) * 512 + ka);
    bfv[1] = *(const short8*)(W2T + (size_t)(wn + 16 + r16) * 512 + ka);
#pragma unroll
    for (int i = 0; i < 2; ++i)
#pragma unroll
      for (int j = 0; j < 2; ++j)
        acc[i][j] = __builtin_amdgcn_mfma_f32_16x16x32_bf16(af[i], bfv[j], acc[i][j], 0, 0, 0);
  }

  // epilogue: C/D layout col=lane&15, row=(lane>>4)*4+p  [m89/m91-verified]
#pragma unroll
  for (int i = 0; i < 2; ++i) {
#pragma unroll
    for (int j = 0; j < 2; ++j) {
#pragma unroll
      for (int p = 0; p < 4; ++p) {
        int prow = i * 16 + q * 4 + p;
        int col = wn + j * 16 + r16;
        int grow = blockIdx.x * 32 + prow;
        if (grow < Nn) out[(size_t)grow * 128 + col] = acc[i][j][p];
      }
    }
  }
}

extern "C" void kernel_launch(void* const* d_in, const int* in_sizes, int n_in,
                              void* d_out, int out_size, void* d_ws, size_t ws_size,
                              hipStream_t stream) {
  const float* X = (const float*)d_in[0];
  const int* esrc = (const int*)d_in[1];
  const int* edst = (const int*)d_in[2];
  const int* erel = (const int*)d_in[3];
  const float* eval_ = (const float*)d_in[4];
  const float* w_bases = (const float*)d_in[5];
  const float* w_rel = (const float*)d_in[6];
  const int Nn = in_sizes[0] / D_IN;  // 100000
  const int E = in_sizes[1];          // 640000

  char* ws = (char*)d_ws;
  size_t off = 0;
  auto alloc = [&](size_t bytes) -> char* {
    char* p = ws + off;
    off += (bytes + 255) & ~(size_t)255;
    return p;
  };
  unsigned short* Xb = (unsigned short*)alloc((size_t)Nn * D_IN * 2);     // 25.6 MB
  unsigned short* W2T = (unsigned short*)alloc((size_t)128 * 512 * 2);    // 128 KB
  int* counts = (int*)alloc((size_t)Nn * 4);
  int* cursor = (int*)alloc((size_t)Nn * 4);
  int* offsets = (int*)alloc((size_t)(Nn + 1) * 4);
  int* localsc = (int*)alloc((size_t)Nn * 4);
  int* bsum = (int*)alloc(4096);
  uint2* bucket = (uint2*)alloc((size_t)(E + 64) * 8);                    // 5.1 MB (+pad)
  (void)ws_size;

  int n4 = Nn * D_IN / 4;  // 3.2M
  hipMemsetAsync(counts, 0, (size_t)Nn * 4, stream);
  k_prep<<<(n4 + 255) / 256, 256, 0, stream>>>((const float4*)X, (ushort4*)Xb, n4,
                                               w_bases, W2T, edst, counts, E);

  int nb = (Nn + 255) / 256;
  k_scan1<<<nb, 256, 0, stream>>>(counts, localsc, bsum, Nn);
  k_scan23<<<nb, 256, 0, stream>>>(localsc, bsum, offsets, cursor, Nn, E);
  k_bucket<<<(E + 255) / 256, 256, 0, stream>>>(esrc, edst, erel, eval_,
                                                cursor, bucket, E);

  // fused aggregation + transform: single dispatch (R17: splits cost ~10us each)
  k_agg_gemm<<<(Nn + 31) / 32, 256, 0, stream>>>(bucket, offsets,
                                                 (const unsigned*)Xb, w_rel, W2T,
                                                 (float*)d_out, Nn);
}

// Round 20
// 243.057 us; speedup vs baseline: 1.1947x; 1.0055x over previous
//
#include <hip/hip_runtime.h>
#include <stdint.h>

#define D_IN 128
#define D_OUT 128
#define NREL 8
#define NBASE 4

typedef __attribute__((ext_vector_type(8))) short short8;
typedef __attribute__((ext_vector_type(4))) float floatx4;
typedef __attribute__((ext_vector_type(2))) float floatx2;

__device__ __forceinline__ unsigned short f2bf(float f) {
  unsigned int u = __float_as_uint(f);
  u += 0x7fffu + ((u >> 16) & 1u);
  return (unsigned short)(u >> 16);
}
__device__ __forceinline__ unsigned pack2bf(float lo, float hi) {
  return (unsigned)f2bf(lo) | ((unsigned)f2bf(hi) << 16);
}
__device__ __forceinline__ float bflo(unsigned int u) { return __uint_as_float(u << 16); }
__device__ __forceinline__ float bfhi(unsigned int u) { return __uint_as_float(u & 0xffff0000u); }

// ---------- 1) prep: cast X fp32->bf16 + build W2T + count (counts zeroed
// by hipMemsetAsync) ----------
// W2T[o][c] = w_bases[b][k][o], c = k*4+b  (bf16, [128][512])
__global__ void k_prep(const float4* __restrict__ X, ushort4* __restrict__ Xb, int n4,
                       const float* __restrict__ w_bases, unsigned short* __restrict__ W2T,
                       const int* __restrict__ edst, int* __restrict__ counts, int E) {
  int i = blockIdx.x * blockDim.x + threadIdx.x;
  if (i < n4) {
    float4 v = X[i];
    ushort4 o;
    o.x = f2bf(v.x); o.y = f2bf(v.y); o.z = f2bf(v.z); o.w = f2bf(v.w);
    Xb[i] = o;
  }
  if (i < 128 * 512) {
    int o = i >> 9, c = i & 511;
    int k = c >> 2, b = c & 3;
    W2T[i] = f2bf(w_bases[(b * D_IN + k) * D_OUT + o]);
  }
  if (i < E) atomicAdd(&counts[edst[i]], 1);
}

// ---------- 2) CSR build (two-kernel scan: R12 proved serial-lookback = 103us) --
__global__ void k_scan1(const int* __restrict__ counts, int* __restrict__ localsc,
                        int* __restrict__ bsum, int Nn) {
  __shared__ int s[256];
  int i = blockIdx.x * 256 + threadIdx.x;
  int v = (i < Nn) ? counts[i] : 0;
  s[threadIdx.x] = v;
  __syncthreads();
  for (int off = 1; off < 256; off <<= 1) {
    int t = 0;
    if (threadIdx.x >= off) t = s[threadIdx.x - off];
    __syncthreads();
    s[threadIdx.x] += t;
    __syncthreads();
  }
  if (i < Nn) localsc[i] = s[threadIdx.x] - v;
  if (threadIdx.x == 255) bsum[blockIdx.x] = s[255];
}

__global__ void k_scan23(const int* __restrict__ localsc, const int* __restrict__ bsum,
                         int* __restrict__ offsets, int* __restrict__ cursor, int Nn, int E) {
  __shared__ int red[256];
  int acc = 0;
  for (int j = threadIdx.x; j < blockIdx.x; j += 256) acc += bsum[j];
  red[threadIdx.x] = acc;
  __syncthreads();
  for (int off = 128; off > 0; off >>= 1) {
    if (threadIdx.x < off) red[threadIdx.x] += red[threadIdx.x + off];
    __syncthreads();
  }
  int pref = red[0];
  int i = blockIdx.x * 256 + threadIdx.x;
  if (i < Nn) {
    int v = localsc[i] + pref;
    offsets[i] = v;
    cursor[i] = v;
  }
  if (i == 0) offsets[Nn] = E;
}

// AoS bucket: ONE 8B uint2 store per edge = (src, (val&~7)|rel).
// [R17 PMC: two 4B scatters -> WRITE 69.7MB for 5.1MB data; one 8B store
// fixed it — bucket left the top-5 in R18.] vr packing verified PASS R6/R15.
__global__ void k_bucket(const int* __restrict__ src, const int* __restrict__ dst,
                         const int* __restrict__ rel, const float* __restrict__ val,
                         int* __restrict__ cursor, uint2* __restrict__ bucket, int E) {
  int i = blockIdx.x * blockDim.x + threadIdx.x;
  if (i >= E) return;
  int d = dst[i];
  int pos = atomicAdd(&cursor[d], 1);
  unsigned vr = (__float_as_uint(val[i]) & ~7u) | (unsigned)rel[i];
  bucket[pos] = make_uint2((unsigned)src[i], vr);
}

// ---------- 3) fused: per-dst basis aggregation (LDS) + MFMA transform ----------
// R15 body (81.3us best). R18 lesson: reading records as uint2 struct loads
// defeated scalar-load selection (records became VMEM dwordx2 -> polluted the
// hand-counted vmcnt(12) and over-drained the gather queue; 81->94us at equal
// FETCH). Fix: read the AoS bucket through a plain u32 pointer (eb32[2t],
// eb32[2t+1]) — the exact load shape R15 measured as s_load at 81.3us —
// while keeping k_bucket's single 8B store.
__global__ __launch_bounds__(256, 4)
void k_agg_gemm(const uint2* __restrict__ ebuck, const int* __restrict__ offsets,
                const unsigned* __restrict__ Xb2, const float* __restrict__ w_rel_g,
                const unsigned short* __restrict__ W2T, float* __restrict__ out, int Nn) {
  __shared__ __align__(16) unsigned short aggS[32][520];  // pitch 520: 2-way alias (free)
  __shared__ __align__(16) float wrS[NREL * NBASE];
  if (threadIdx.x < NREL * NBASE) wrS[threadIdx.x] = w_rel_g[threadIdx.x];
  __syncthreads();

  const unsigned* __restrict__ eb32 = (const unsigned*)ebuck;
  const int wave = threadIdx.x >> 6, lane = threadIdx.x & 63;
  const int d0 = blockIdx.x * 32 + wave * 8;
  const floatx2 zf2 = {0.f, 0.f};
  const uint64_t xbase = (uint64_t)Xb2;       // byte base of bf16x2 rows (256B/row)
  const unsigned loff = (unsigned)lane * 4u;  // per-lane byte offset (VGPR)

  // lane l (0..8) loads offsets[d0+l]; readlane -> SGPR bounds
  int oidx = d0 + (lane < 8 ? lane : 8);
  if (oidx > Nn) oidx = Nn;
  const int offv = offsets[oidx];
  const int s0 = __builtin_amdgcn_readlane(offv, 0);
  const int e8 = __builtin_amdgcn_readlane(offv, 8);

  floatx2 a0 = zf2, a1 = zf2, a2 = zf2, a3 = zf2;
  int row = 0;
  int bnd = __builtin_amdgcn_readlane(offv, 1);

#define FLUSH()                                                      \
  do {                                                               \
    uint4 o_;                                                        \
    o_.x = pack2bf(a0.x, a1.x);                                      \
    o_.y = pack2bf(a2.x, a3.x);                                      \
    o_.z = pack2bf(a0.y, a1.y);                                      \
    o_.w = pack2bf(a2.y, a3.y);                                      \
    *(uint4*)&aggS[wave * 8 + row][lane * 8] = o_;                   \
    a0 = zf2; a1 = zf2; a2 = zf2; a3 = zf2;                          \
    ++row;                                                           \
    bnd = (row < 8) ? __builtin_amdgcn_readlane(offv, row + 1)       \
                    : 0x7fffffff;                                    \
  } while (0)

  // SREC: 4 records as PLAIN U32 scalar loads (s_load; clamped over-issue
  // re-reads record ce — same cache line, no fetch inflation)
#define SREC(S, BASE)                                                \
  do {                                                               \
    int b_ = (BASE);                                                 \
    int t0_ = b_ < ce ? b_ : ce;                                     \
    int t1_ = b_ + 1 < ce ? b_ + 1 : ce;                             \
    int t2_ = b_ + 2 < ce ? b_ + 2 : ce;                             \
    int t3_ = b_ + 3 < ce ? b_ + 3 : ce;                             \
    s##S##0 = eb32[2 * t0_]; r##S##0 = eb32[2 * t0_ + 1];            \
    s##S##1 = eb32[2 * t1_]; r##S##1 = eb32[2 * t1_ + 1];            \
    s##S##2 = eb32[2 * t2_]; r##S##2 = eb32[2 * t2_ + 1];            \
    s##S##3 = eb32[2 * t3_]; r##S##3 = eb32[2 * t3_ + 1];            \
  } while (0)

  // GLOAD: inline-asm gather (pinned — compiler can't sink/remat asm outputs)
#define GLOAD(Y, SRCID)                                              \
  do {                                                               \
    uint64_t ga_ = xbase + ((uint64_t)(SRCID) << 8);                 \
    asm volatile("global_load_dword %0, %1, %2"                      \
                 : "=v"(Y) : "v"(loff), "s"(ga_));                   \
  } while (0)

#define GATH(S)                                                      \
  do {                                                               \
    GLOAD(y##S##0, s##S##0); GLOAD(y##S##1, s##S##1);                \
    GLOAD(y##S##2, s##S##2); GLOAD(y##S##3, s##S##3);                \
  } while (0)

  // COEF: 4 edges' float4 coef = val * w_rel[rel] via LDS broadcast + muls
#define COEF1(C, RV)                                                 \
  do {                                                               \
    const float4 w_ = *(const float4*)&wrS[((RV) & 7u) * 4];         \
    const float v_ = __uint_as_float((RV) & ~7u);                    \
    (C) = make_float4(v_ * w_.x, v_ * w_.y, v_ * w_.z, v_ * w_.w);   \
  } while (0)

#define COEF(S)                                                      \
  do {                                                               \
    COEF1(c##S##0, r##S##0); COEF1(c##S##1, r##S##1);                \
    COEF1(c##S##2, r##S##2); COEF1(c##S##3, r##S##3);                \
  } while (0)

  // WAITG: oldest slot's 4 gathers done (3 younger slots = 12 remain);
  // sched_barrier fences the region (rule 18) AND pins the slot pipeline.
#define WAITG()                                                      \
  do {                                                               \
    asm volatile("s_waitcnt vmcnt(12)" ::: "memory");                \
    __builtin_amdgcn_sched_barrier(0);                               \
  } while (0)

  // ACCT1: one edge: scalar guard + boundary flush + 2 unpack + 8 fma
#define ACCT1(EI, C, Y)                                              \
  do {                                                               \
    if ((EI) < e8) {                                                 \
      while ((EI) == bnd) FLUSH();                                   \
      floatx2 x_;                                                    \
      x_.x = bflo(Y);                                                \
      x_.y = bfhi(Y);                                                \
      a0 += (C).x * x_;                                              \
      a1 += (C).y * x_;                                              \
      a2 += (C).z * x_;                                              \
      a3 += (C).w * x_;                                              \
    }                                                                \
  } while (0)

#define ACCT4(S, EI0)                                                \
  do {                                                               \
    ACCT1((EI0), c##S##0, y##S##0);                                  \
    ACCT1((EI0) + 1, c##S##1, y##S##1);                              \
    ACCT1((EI0) + 2, c##S##2, y##S##2);                              \
    ACCT1((EI0) + 3, c##S##3, y##S##3);                              \
  } while (0)

  if (s0 < e8) {
    const int ce = e8 - 1;
    unsigned s00, s01, s02, s03, s10, s11, s12, s13, s20, s21, s22, s23;
    unsigned s30, s31, s32, s33, s40, s41, s42, s43, s50, s51, s52, s53;
    unsigned r00, r01, r02, r03, r10, r11, r12, r13, r20, r21, r22, r23;
    unsigned r30, r31, r32, r33, r40, r41, r42, r43, r50, r51, r52, r53;
    unsigned y00, y01, y02, y03, y10, y11, y12, y13, y20, y21, y22, y23;
    unsigned y30, y31, y32, y33, y40, y41, y42, y43, y50, y51, y52, y53;
    float4 c00, c01, c02, c03, c10, c11, c12, c13, c20, c21, c22, c23;
    float4 c30, c31, c32, c33, c40, c41, c42, c43, c50, c51, c52, c53;
    // prologue: records for slots 0-4, gathers 0-2, coefs 0-1
    SREC(0, s0); SREC(1, s0 + 4); SREC(2, s0 + 8);
    SREC(3, s0 + 12); SREC(4, s0 + 16);
    GATH(0); GATH(1); GATH(2);
    COEF(0); COEF(1);
    int gi = s0;
    while (gi < e8) {
      // j=0
      GATH(3); SREC(5, gi + 20); COEF(2); WAITG(); ACCT4(0, gi);
      // j=1
      GATH(4); SREC(0, gi + 24); COEF(3); WAITG(); ACCT4(1, gi + 4);
      // j=2
      GATH(5); SREC(1, gi + 28); COEF(4); WAITG(); ACCT4(2, gi + 8);
      // j=3
      GATH(0); SREC(2, gi + 32); COEF(5); WAITG(); ACCT4(3, gi + 12);
      // j=4
      GATH(1); SREC(3, gi + 36); COEF(0); WAITG(); ACCT4(4, gi + 16);
      // j=5
      GATH(2); SREC(4, gi + 40); COEF(1); WAITG(); ACCT4(5, gi + 20);
      gi += 24;
    }
    // Drain: 12 outstanding tail gathers + pending s_loads must land BEFORE
    // their registers are reused (fenced both sides).
    __builtin_amdgcn_sched_barrier(0);
    asm volatile("s_waitcnt vmcnt(0) lgkmcnt(0)" ::: "memory");
    __builtin_amdgcn_sched_barrier(0);
  }
  while (row < 8) FLUSH();  // trailing (and fully-empty) rows

  __syncthreads();

  // ---- phase 2: 32x128 output tile via 16x16x32 MFMA, K=512 ----
  const int q = lane >> 4, r16 = lane & 15;
  const int wn = wave * 32;
  const floatx4 zero = {0.f, 0.f, 0.f, 0.f};
  floatx4 acc[2][2];
  acc[0][0] = zero; acc[0][1] = zero; acc[1][0] = zero; acc[1][1] = zero;

#pragma unroll 4
  for (int k0 = 0; k0 < 512; k0 += 32) {
    int ka = k0 + q * 8;
    short8 af[2], bfv[2];
    af[0] = *(const short8*)&aggS[r16][ka];
    af[1] = *(const short8*)&aggS[16 + r16][ka];
    bfv[0] = *(const short8*)(W2T + (size_t)(wn + r16) * 512 + ka);
    bfv[1] = *(const short8*)(W2T + (size_t)(wn + 16 + r16) * 512 + ka);
#pragma unroll
    for (int i = 0; i < 2; ++i)
#pragma unroll
      for (int j = 0; j < 2; ++j)
        acc[i][j] = __builtin_amdgcn_mfma_f32_16x16x32_bf16(af[i], bfv[j], acc[i][j], 0, 0, 0);
  }

  // epilogue: C/D layout col=lane&15, row=(lane>>4)*4+p  [m89/m91-verified]
#pragma unroll
  for (int i = 0; i < 2; ++i) {
#pragma unroll
    for (int j = 0; j < 2; ++j) {
#pragma unroll
      for (int p = 0; p < 4; ++p) {
        int prow = i * 16 + q * 4 + p;
        int col = wn + j * 16 + r16;
        int grow = blockIdx.x * 32 + prow;
        if (grow < Nn) out[(size_t)grow * 128 + col] = acc[i][j][p];
      }
    }
  }
}

extern "C" void kernel_launch(void* const* d_in, const int* in_sizes, int n_in,
                              void* d_out, int out_size, void* d_ws, size_t ws_size,
                              hipStream_t stream) {
  const float* X = (const float*)d_in[0];
  const int* esrc = (const int*)d_in[1];
  const int* edst = (const int*)d_in[2];
  const int* erel = (const int*)d_in[3];
  const float* eval_ = (const float*)d_in[4];
  const float* w_bases = (const float*)d_in[5];
  const float* w_rel = (const float*)d_in[6];
  const int Nn = in_sizes[0] / D_IN;  // 100000
  const int E = in_sizes[1];          // 640000

  char* ws = (char*)d_ws;
  size_t off = 0;
  auto alloc = [&](size_t bytes) -> char* {
    char* p = ws + off;
    off += (bytes + 255) & ~(size_t)255;
    return p;
  };
  unsigned short* Xb = (unsigned short*)alloc((size_t)Nn * D_IN * 2);     // 25.6 MB
  unsigned short* W2T = (unsigned short*)alloc((size_t)128 * 512 * 2);    // 128 KB
  int* counts = (int*)alloc((size_t)Nn * 4);
  int* cursor = (int*)alloc((size_t)Nn * 4);
  int* offsets = (int*)alloc((size_t)(Nn + 1) * 4);
  int* localsc = (int*)alloc((size_t)Nn * 4);
  int* bsum = (int*)alloc(4096);
  uint2* bucket = (uint2*)alloc((size_t)(E + 64) * 8);                    // 5.1 MB (+pad)
  (void)ws_size;

  int n4 = Nn * D_IN / 4;  // 3.2M
  hipMemsetAsync(counts, 0, (size_t)Nn * 4, stream);
  k_prep<<<(n4 + 255) / 256, 256, 0, stream>>>((const float4*)X, (ushort4*)Xb, n4,
                                               w_bases, W2T, edst, counts, E);

  int nb = (Nn + 255) / 256;
  k_scan1<<<nb, 256, 0, stream>>>(counts, localsc, bsum, Nn);
  k_scan23<<<nb, 256, 0, stream>>>(localsc, bsum, offsets, cursor, Nn, E);
  k_bucket<<<(E + 255) / 256, 256, 0, stream>>>(esrc, edst, erel, eval_,
                                                cursor, bucket, E);

  // fused aggregation + transform: single dispatch
  k_agg_gemm<<<(Nn + 31) / 32, 256, 0, stream>>>(bucket, offsets,
                                                 (const unsigned*)Xb, w_rel, W2T,
                                                 (float*)d_out, Nn);
}